// Round 1
// baseline (789.121 us; speedup 1.0000x reference)
//
#include <hip/hip_runtime.h>

// VQ-VAE fused forward on gfx950 — v2 (occupancy + proto-folded scoring).
// Per 64-row block: x --[G1 K=512]--> h1(64) --[G2]--> h2(256) in LDS.
// Then, from h2s only:
//   G3: lat = h2 @ Wmu^T + bmu in REGS, accumulate ||lat||^2 partials.
//   G4: score = h2 @ P2[p]^T + cinit[p]  (= p.lat - ||p||^2/2), argmax with
//       proto index packed into low 10 mantissa bits of the f32 key.
// loss_row = -2*max_key + ||lat||^2 ; out rows = exact f32 gather protos[idx].
// LDS = 40 KB -> 4 blocks/CU (16 waves/CU vs previous 8).

typedef unsigned short u16;
typedef float f32x4 __attribute__((ext_vector_type(4)));
typedef __bf16 bf16x8 __attribute__((ext_vector_type(8)));
typedef unsigned short u16x8 __attribute__((ext_vector_type(8)));

#define N_ROWS 131072
#define IN_D 512
#define HID_D 64
#define OUT_D 256
#define K_P 1024

__device__ __forceinline__ u16 f2bfn(float f) {
  return __builtin_bit_cast(u16, (__bf16)f);
}
__device__ __forceinline__ f32x4 mfma16(u16x8 a, u16x8 b, f32x4 c) {
  return __builtin_amdgcn_mfma_f32_16x16x32_bf16(
      __builtin_bit_cast(bf16x8, a), __builtin_bit_cast(bf16x8, b), c, 0, 0, 0);
}
// XOR-swizzled LDS addressing (u16 units), 16B chunks.
__device__ __forceinline__ int sw64(int row, int col) {   // [64][64]
  return row * 64 + ((((col >> 3) ^ (row & 7)) & 7) << 3) + (col & 7);
}
__device__ __forceinline__ int sw256(int row, int col) {  // [64][256]
  return row * 256 + ((((col >> 3) ^ (row & 15)) & 31) << 3) + (col & 7);
}

// ---------------- prep kernels ----------------
__global__ void prep_w(const float* __restrict__ W1, const float* __restrict__ W2,
                       const float* __restrict__ Wmu, u16* __restrict__ w1b,
                       u16* __restrict__ w2b, u16* __restrict__ wmub,
                       float* __restrict__ loss_accum) {
  int i = blockIdx.x * 256 + threadIdx.x;   // grid 448*256 = 114688 exactly
  if (i == 0) *loss_accum = 0.f;
  if (i < 32768) {
    w1b[i] = f2bfn(W1[i]);
  } else if (i < 49152) {
    w2b[i - 32768] = f2bfn(W2[i - 32768]);
  } else {
    wmub[i - 49152] = f2bfn(Wmu[i - 49152]);
  }
}

// P2[p][k] = sum_j protos[p][j] * Wmu[j][k]  (f32 accum, bf16 store)
// cinit[p] = protos[p].bmu - 0.5*||protos[p]||^2   (f32)
__global__ void prep_p(const float* __restrict__ protos, const float* __restrict__ Wmu,
                       const float* __restrict__ bmu, u16* __restrict__ p2b,
                       float* __restrict__ cinit) {
  __shared__ float prow[4][256];
  const int b = blockIdx.x, t = threadIdx.x;   // 256 blocks x 4 protos
  const int wv = t >> 6, lane = t & 63;
  #pragma unroll
  for (int i = 0; i < 4; i++) prow[i][t] = protos[(b * 4 + i) * 256 + t];
  __syncthreads();
  float a0 = 0.f, a1 = 0.f, a2 = 0.f, a3 = 0.f;
  #pragma unroll 4
  for (int j = 0; j < 256; j++) {
    float w = Wmu[j * 256 + t];
    a0 += prow[0][j] * w; a1 += prow[1][j] * w;
    a2 += prow[2][j] * w; a3 += prow[3][j] * w;
  }
  p2b[(b * 4 + 0) * 256 + t] = f2bfn(a0);
  p2b[(b * 4 + 1) * 256 + t] = f2bfn(a1);
  p2b[(b * 4 + 2) * 256 + t] = f2bfn(a2);
  p2b[(b * 4 + 3) * 256 + t] = f2bfn(a3);
  // wave wv reduces proto b*4+wv
  float part = 0.f;
  #pragma unroll
  for (int c = 0; c < 4; c++) {
    float v = prow[wv][lane + c * 64];
    part += v * bmu[lane + c * 64] - 0.5f * v * v;
  }
  for (int off = 32; off; off >>= 1) part += __shfl_xor(part, off, 64);
  if (lane == 0) cinit[b * 4 + wv] = part;
}

__global__ void fin(const float* __restrict__ loss_accum, float* __restrict__ out) {
  out[(size_t)N_ROWS * OUT_D] = loss_accum[0] * (1.25f / ((float)N_ROWS * (float)OUT_D));
  out[(size_t)N_ROWS * OUT_D + 1] = 0.f;  // capacity
}

// ---------------- fused main kernel ----------------
__global__ __launch_bounds__(256, 4) void vq_fused(
    const float* __restrict__ x, const float* __restrict__ b1,
    const float* __restrict__ b2, const float* __restrict__ bmu,
    const float* __restrict__ protos, const u16* __restrict__ w1b,
    const u16* __restrict__ w2b, const u16* __restrict__ wmub,
    const u16* __restrict__ p2b, const float* __restrict__ cinit,
    float* __restrict__ out, float* __restrict__ loss_accum) {
  __shared__ uint4 smem4[2560];                  // 40 KB exactly -> 4 blocks/CU
  u16* hA = (u16*)smem4;                         // 8 KB: xs chunk -> h1 -> scratch
  u16* hB = (u16*)smem4 + 4096;                  // 32 KB: h2s [64][256]

  const int tid = threadIdx.x;
  const int wave = tid >> 6;
  const int lane = tid & 63;
  const int quad = lane >> 4;
  const int l15 = lane & 15;
  const long rowbase = (long)blockIdx.x * 64;

  // ===== GEMM1: h1 = relu(x @ W1^T + b1); K=512 in 8 chunks of 64 =====
  u16x8 w1f[16];                                 // all W1 B-frags hoisted (64 VGPR)
  #pragma unroll
  for (int s = 0; s < 16; s++)
    w1f[s] = *((const u16x8*)(w1b + (wave * 16 + l15) * IN_D + s * 32 + quad * 8));

  f32x4 acc1[4];
  #pragma unroll
  for (int mt = 0; mt < 4; mt++) acc1[mt] = (f32x4){0.f, 0.f, 0.f, 0.f};

  const int sr = tid >> 2, sseg = tid & 3;       // stage: 4 threads/row, 16 f32 each
  const float* xrow = x + (rowbase + sr) * IN_D + sseg * 16;
  f32x4 xv[4];
  #pragma unroll
  for (int j = 0; j < 4; j++) xv[j] = ((const f32x4*)xrow)[j];

  #pragma unroll
  for (int kc = 0; kc < 8; kc++) {
    u16x8 h0, h1v;
    h0[0] = f2bfn(xv[0][0]); h0[1] = f2bfn(xv[0][1]);
    h0[2] = f2bfn(xv[0][2]); h0[3] = f2bfn(xv[0][3]);
    h0[4] = f2bfn(xv[1][0]); h0[5] = f2bfn(xv[1][1]);
    h0[6] = f2bfn(xv[1][2]); h0[7] = f2bfn(xv[1][3]);
    h1v[0] = f2bfn(xv[2][0]); h1v[1] = f2bfn(xv[2][1]);
    h1v[2] = f2bfn(xv[2][2]); h1v[3] = f2bfn(xv[2][3]);
    h1v[4] = f2bfn(xv[3][0]); h1v[5] = f2bfn(xv[3][1]);
    h1v[6] = f2bfn(xv[3][2]); h1v[7] = f2bfn(xv[3][3]);
    if (kc < 7) {                                // issue next chunk early (T14)
      const float* xn = xrow + (kc + 1) * 64;
      #pragma unroll
      for (int j = 0; j < 4; j++) xv[j] = ((const f32x4*)xn)[j];
    }
    __syncthreads();                             // prev chunk's frag reads done
    *((u16x8*)(hA + sw64(sr, sseg * 16))) = h0;
    *((u16x8*)(hA + sw64(sr, sseg * 16 + 8))) = h1v;
    __syncthreads();
    #pragma unroll
    for (int s = 0; s < 2; s++) {
      u16x8 bf = w1f[kc * 2 + s];
      #pragma unroll
      for (int mt = 0; mt < 4; mt++) {
        u16x8 af = *((const u16x8*)(hA + sw64(mt * 16 + l15, s * 32 + quad * 8)));
        acc1[mt] = mfma16(af, bf, acc1[mt]);
      }
    }
  }
  __syncthreads();                               // xs dead; hA becomes h1
  {
    float bias = b1[wave * 16 + l15];            // wave owns hid cols w*16..+15
    #pragma unroll
    for (int mt = 0; mt < 4; mt++)
      #pragma unroll
      for (int r = 0; r < 4; r++) {
        float v = acc1[mt][r] + bias;
        hA[sw64(mt * 16 + quad * 4 + r, wave * 16 + l15)] = f2bfn(v > 0.f ? v : 0.f);
      }
  }
  __syncthreads();                               // h1 complete

  // ===== GEMM2: h2 = relu(h1 @ W2^T + b2), K=64; wave owns cols w*64..+63 =====
  {
    u16x8 b2f[4][2];
    float bias2[4];
    #pragma unroll
    for (int nt = 0; nt < 4; nt++) {
      int col = wave * 64 + nt * 16 + l15;
      bias2[nt] = b2[col];
      #pragma unroll
      for (int s = 0; s < 2; s++)
        b2f[nt][s] = *((const u16x8*)(w2b + col * HID_D + s * 32 + quad * 8));
    }
    #pragma unroll
    for (int mt = 0; mt < 4; mt++) {
      u16x8 a0 = *((const u16x8*)(hA + sw64(mt * 16 + l15, 0 + quad * 8)));
      u16x8 a1 = *((const u16x8*)(hA + sw64(mt * 16 + l15, 32 + quad * 8)));
      #pragma unroll
      for (int nt = 0; nt < 4; nt++) {
        f32x4 acc = (f32x4){0.f, 0.f, 0.f, 0.f};
        acc = mfma16(a0, b2f[nt][0], acc);
        acc = mfma16(a1, b2f[nt][1], acc);
        #pragma unroll
        for (int r = 0; r < 4; r++) {
          float v = acc[r] + bias2[nt];
          hB[sw256(mt * 16 + quad * 4 + r, wave * 64 + nt * 16 + l15)] =
              f2bfn(v > 0.f ? v : 0.f);
        }
      }
    }
  }
  __syncthreads();                               // h2s complete; hA free (scratch)

  float* wnorm = (float*)hA;                     // [4][64] rownorm partials
  float* wkey = (float*)hA + 256;                // [4][64] packed max keys
  int* idxs = (int*)((float*)hA + 512);          // [64]

  // ===== G3: lat in regs -> rownorm partials (wave owns cols w*64..+63) =====
  {
    float rn[16];
    #pragma unroll
    for (int i = 0; i < 16; i++) rn[i] = 0.f;
    #pragma unroll
    for (int np = 0; np < 2; np++) {
      u16x8 b3f[2][8];
      float bias3[2];
      #pragma unroll
      for (int tt = 0; tt < 2; tt++) {
        int col = wave * 64 + (np * 2 + tt) * 16 + l15;
        bias3[tt] = bmu[col];
        #pragma unroll
        for (int s = 0; s < 8; s++)
          b3f[tt][s] = *((const u16x8*)(wmub + col * OUT_D + s * 32 + quad * 8));
      }
      #pragma unroll
      for (int mt = 0; mt < 4; mt++) {
        f32x4 aa = (f32x4){0.f, 0.f, 0.f, 0.f}, ab = (f32x4){0.f, 0.f, 0.f, 0.f};
        #pragma unroll
        for (int s = 0; s < 8; s++) {
          u16x8 af = *((const u16x8*)(hB + sw256(mt * 16 + l15, s * 32 + quad * 8)));
          aa = mfma16(af, b3f[0][s], aa);
          ab = mfma16(af, b3f[1][s], ab);
        }
        #pragma unroll
        for (int r = 0; r < 4; r++) {
          float v0 = aa[r] + bias3[0];           // NO relu on lat
          float v1 = ab[r] + bias3[1];
          rn[mt * 4 + r] += v0 * v0 + v1 * v1;
        }
      }
    }
    #pragma unroll
    for (int off = 1; off < 16; off <<= 1)
      #pragma unroll
      for (int i = 0; i < 16; i++) rn[i] += __shfl_xor(rn[i], off, 64);
    if (l15 == 0)
      #pragma unroll
      for (int mt = 0; mt < 4; mt++)
        #pragma unroll
        for (int r = 0; r < 4; r++)
          wnorm[wave * 64 + mt * 16 + quad * 4 + r] = rn[mt * 4 + r];
  }

  // ===== G4: argmax_p (h2.P2[p] + cinit[p]); wave owns protos w*256..+255 =====
  {
    float mk[16];
    #pragma unroll
    for (int i = 0; i < 16; i++) mk[i] = -3.4e38f;
    #pragma unroll
    for (int g = 0; g < 8; g++) {
      int p0 = wave * 256 + g * 32;
      u16x8 bpf[2][8];
      #pragma unroll
      for (int tt = 0; tt < 2; tt++)
        #pragma unroll
        for (int s = 0; s < 8; s++)
          bpf[tt][s] =
              *((const u16x8*)(p2b + (p0 + tt * 16 + l15) * OUT_D + s * 32 + quad * 8));
      float c0 = cinit[p0 + l15];
      float c1 = cinit[p0 + 16 + l15];
      unsigned i0 = (unsigned)(p0 + l15), i1 = (unsigned)(p0 + 16 + l15);
      #pragma unroll
      for (int mt = 0; mt < 4; mt++) {
        f32x4 aa = (f32x4){c0, c0, c0, c0};
        f32x4 ab = (f32x4){c1, c1, c1, c1};
        #pragma unroll
        for (int s = 0; s < 8; s++) {
          u16x8 af = *((const u16x8*)(hB + sw256(mt * 16 + l15, s * 32 + quad * 8)));
          aa = mfma16(af, bpf[0][s], aa);
          ab = mfma16(af, bpf[1][s], ab);
        }
        #pragma unroll
        for (int r = 0; r < 4; r++) {
          unsigned ka = (__builtin_bit_cast(unsigned, aa[r]) & 0xFFFFFC00u) | i0;
          unsigned kb = (__builtin_bit_cast(unsigned, ab[r]) & 0xFFFFFC00u) | i1;
          mk[mt * 4 + r] = fmaxf(fmaxf(mk[mt * 4 + r], __builtin_bit_cast(float, ka)),
                                 __builtin_bit_cast(float, kb));
        }
      }
    }
    #pragma unroll
    for (int off = 1; off < 16; off <<= 1)
      #pragma unroll
      for (int i = 0; i < 16; i++) mk[i] = fmaxf(mk[i], __shfl_xor(mk[i], off, 64));
    if (l15 == 0)
      #pragma unroll
      for (int mt = 0; mt < 4; mt++)
        #pragma unroll
        for (int r = 0; r < 4; r++)
          wkey[wave * 64 + mt * 16 + quad * 4 + r] = mk[mt * 4 + r];
  }
  __syncthreads();

  // ===== final per-row reduce: idx, loss_row = -2*maxkey + ||lat||^2 =====
  if (tid < 64) {
    float k = wkey[tid];
    k = fmaxf(k, wkey[64 + tid]);
    k = fmaxf(k, wkey[128 + tid]);
    k = fmaxf(k, wkey[192 + tid]);
    float nrm = wnorm[tid] + wnorm[64 + tid] + wnorm[128 + tid] + wnorm[192 + tid];
    idxs[tid] = (int)(__builtin_bit_cast(unsigned, k) & 1023u);
    float lrow = nrm - 2.f * k;
    for (int off = 32; off; off >>= 1) lrow += __shfl_xor(lrow, off, 64);
    if (tid == 0) atomicAdd(loss_accum, lrow);
  }
  __syncthreads();

  // ===== epilogue: out = protos[idx] (exact f32 gather) =====
  {
    int r = tid >> 2, seg = tid & 3;
    int idx = idxs[r];
    const f32x4* qp = (const f32x4*)(protos + (size_t)idx * OUT_D + seg * 64);
    f32x4* op = (f32x4*)(out + (rowbase + r) * OUT_D + seg * 64);
    #pragma unroll
    for (int j = 0; j < 16; j++) op[j] = qp[j];
  }
}

extern "C" void kernel_launch(void* const* d_in, const int* in_sizes, int n_in,
                              void* d_out, int out_size, void* d_ws, size_t ws_size,
                              hipStream_t stream) {
  const float* x = (const float*)d_in[0];
  const float* W1 = (const float*)d_in[1];
  const float* b1 = (const float*)d_in[2];
  const float* W2 = (const float*)d_in[3];
  const float* b2 = (const float*)d_in[4];
  const float* Wmu = (const float*)d_in[5];
  const float* bmu = (const float*)d_in[6];
  const float* protos = (const float*)d_in[7];
  char* ws = (char*)d_ws;
  u16* p2b = (u16*)ws;                           // 512 KB  (protos @ Wmu, bf16)
  u16* w1b = (u16*)(ws + 524288);                // 64 KB
  u16* w2b = (u16*)(ws + 589824);                // 32 KB
  u16* wmub = (u16*)(ws + 622592);               // 128 KB
  float* cinit = (float*)(ws + 753664);          // 4 KB
  float* loss = (float*)(ws + 757760);           // 4 B
  float* out = (float*)d_out;

  prep_w<<<dim3(448), dim3(256), 0, stream>>>(W1, W2, Wmu, w1b, w2b, wmub, loss);
  prep_p<<<dim3(256), dim3(256), 0, stream>>>(protos, Wmu, bmu, p2b, cinit);
  vq_fused<<<dim3(2048), dim3(256), 0, stream>>>(x, b1, b2, bmu, protos, w1b, w2b,
                                                 wmub, p2b, cinit, out, loss);
  fin<<<dim3(1), dim3(1), 0, stream>>>(loss, out);
}

// Round 2
// 768.649 us; speedup vs baseline: 1.0266x; 1.0266x over previous
//
#include <hip/hip_runtime.h>

// VQ-VAE fused forward on gfx950 — v3 (cache-pollution control).
// v2 structure (proto-folded scoring, 40 KB LDS, 4 blocks/CU) unchanged.
// New: non-temporal x loads + lane-remapped non-temporal out stores (full
// 64B-line coverage per instruction) + bijective XCD block swizzle, so the
// one-shot x/out streams stop evicting the shared bf16 weight arrays
// (p2b/wmub/w1b/w2b ~2.2 MB) from L2/L3.

typedef unsigned short u16;
typedef float f32x4 __attribute__((ext_vector_type(4)));
typedef __bf16 bf16x8 __attribute__((ext_vector_type(8)));
typedef unsigned short u16x8 __attribute__((ext_vector_type(8)));
typedef unsigned short u16x4 __attribute__((ext_vector_type(4)));

#define N_ROWS 131072
#define IN_D 512
#define HID_D 64
#define OUT_D 256
#define K_P 1024

__device__ __forceinline__ u16 f2bfn(float f) {
  return __builtin_bit_cast(u16, (__bf16)f);
}
__device__ __forceinline__ f32x4 mfma16(u16x8 a, u16x8 b, f32x4 c) {
  return __builtin_amdgcn_mfma_f32_16x16x32_bf16(
      __builtin_bit_cast(bf16x8, a), __builtin_bit_cast(bf16x8, b), c, 0, 0, 0);
}
// XOR-swizzled LDS addressing (u16 units), 8-col chunks stay contiguous.
__device__ __forceinline__ int sw64(int row, int col) {   // [64][64]
  return row * 64 + ((((col >> 3) ^ (row & 7)) & 7) << 3) + (col & 7);
}
__device__ __forceinline__ int sw256(int row, int col) {  // [64][256]
  return row * 256 + ((((col >> 3) ^ (row & 15)) & 31) << 3) + (col & 7);
}

// ---------------- prep kernels ----------------
__global__ void prep_w(const float* __restrict__ W1, const float* __restrict__ W2,
                       const float* __restrict__ Wmu, u16* __restrict__ w1b,
                       u16* __restrict__ w2b, u16* __restrict__ wmub,
                       float* __restrict__ loss_accum) {
  int i = blockIdx.x * 256 + threadIdx.x;   // grid 448*256 = 114688 exactly
  if (i == 0) *loss_accum = 0.f;
  if (i < 32768) {
    w1b[i] = f2bfn(W1[i]);
  } else if (i < 49152) {
    w2b[i - 32768] = f2bfn(W2[i - 32768]);
  } else {
    wmub[i - 49152] = f2bfn(Wmu[i - 49152]);
  }
}

// P2[p][k] = sum_j protos[p][j] * Wmu[j][k]  (f32 accum, bf16 store)
// cinit[p] = protos[p].bmu - 0.5*||protos[p]||^2   (f32)
__global__ void prep_p(const float* __restrict__ protos, const float* __restrict__ Wmu,
                       const float* __restrict__ bmu, u16* __restrict__ p2b,
                       float* __restrict__ cinit) {
  __shared__ float prow[4][256];
  const int b = blockIdx.x, t = threadIdx.x;   // 256 blocks x 4 protos
  const int wv = t >> 6, lane = t & 63;
  #pragma unroll
  for (int i = 0; i < 4; i++) prow[i][t] = protos[(b * 4 + i) * 256 + t];
  __syncthreads();
  float a0 = 0.f, a1 = 0.f, a2 = 0.f, a3 = 0.f;
  #pragma unroll 4
  for (int j = 0; j < 256; j++) {
    float w = Wmu[j * 256 + t];
    a0 += prow[0][j] * w; a1 += prow[1][j] * w;
    a2 += prow[2][j] * w; a3 += prow[3][j] * w;
  }
  p2b[(b * 4 + 0) * 256 + t] = f2bfn(a0);
  p2b[(b * 4 + 1) * 256 + t] = f2bfn(a1);
  p2b[(b * 4 + 2) * 256 + t] = f2bfn(a2);
  p2b[(b * 4 + 3) * 256 + t] = f2bfn(a3);
  // wave wv reduces proto b*4+wv
  float part = 0.f;
  #pragma unroll
  for (int c = 0; c < 4; c++) {
    float v = prow[wv][lane + c * 64];
    part += v * bmu[lane + c * 64] - 0.5f * v * v;
  }
  for (int off = 32; off; off >>= 1) part += __shfl_xor(part, off, 64);
  if (lane == 0) cinit[b * 4 + wv] = part;
}

__global__ void fin(const float* __restrict__ loss_accum, float* __restrict__ out) {
  out[(size_t)N_ROWS * OUT_D] = loss_accum[0] * (1.25f / ((float)N_ROWS * (float)OUT_D));
  out[(size_t)N_ROWS * OUT_D + 1] = 0.f;  // capacity
}

// ---------------- fused main kernel ----------------
__global__ __launch_bounds__(256, 4) void vq_fused(
    const float* __restrict__ x, const float* __restrict__ b1,
    const float* __restrict__ b2, const float* __restrict__ bmu,
    const float* __restrict__ protos, const u16* __restrict__ w1b,
    const u16* __restrict__ w2b, const u16* __restrict__ wmub,
    const u16* __restrict__ p2b, const float* __restrict__ cinit,
    float* __restrict__ out, float* __restrict__ loss_accum) {
  __shared__ uint4 smem4[2560];                  // 40 KB exactly -> 4 blocks/CU
  u16* hA = (u16*)smem4;                         // 8 KB: xs chunk -> h1 -> scratch
  u16* hB = (u16*)smem4 + 4096;                  // 32 KB: h2s [64][256]

  const int tid = threadIdx.x;
  const int wave = tid >> 6;
  const int lane = tid & 63;
  const int quad = lane >> 4;
  const int l15 = lane & 15;
  // bijective XCD swizzle: 2048 blocks = 8 XCDs x 256 contiguous tiles
  const int bid = blockIdx.x;
  const int swz = (bid & 7) * 256 + (bid >> 3);
  const long rowbase = (long)swz * 64;

  // ===== GEMM1: h1 = relu(x @ W1^T + b1); K=512 in 8 chunks of 64 =====
  u16x8 w1f[16];                                 // all W1 B-frags hoisted
  #pragma unroll
  for (int s = 0; s < 16; s++)
    w1f[s] = *((const u16x8*)(w1b + (wave * 16 + l15) * IN_D + s * 32 + quad * 8));

  f32x4 acc1[4];
  #pragma unroll
  for (int mt = 0; mt < 4; mt++) acc1[mt] = (f32x4){0.f, 0.f, 0.f, 0.f};

  // stage map: 4 threads/row; per INSTRUCTION lanes 0-3 cover one full 64B line
  const int sr = tid >> 2, c4 = tid & 3;
  const float* xrow = x + (rowbase + sr) * IN_D;
  f32x4 xv[4];
  #pragma unroll
  for (int j = 0; j < 4; j++)
    xv[j] = __builtin_nontemporal_load(((const f32x4*)xrow) + c4 + 4 * j);

  #pragma unroll
  for (int kc = 0; kc < 8; kc++) {
    u16x4 hv[4];
    #pragma unroll
    for (int j = 0; j < 4; j++) {
      hv[j][0] = f2bfn(xv[j][0]); hv[j][1] = f2bfn(xv[j][1]);
      hv[j][2] = f2bfn(xv[j][2]); hv[j][3] = f2bfn(xv[j][3]);
    }
    if (kc < 7) {                                // issue next chunk early (T14)
      const f32x4* xn = (const f32x4*)(xrow + (kc + 1) * 64);
      #pragma unroll
      for (int j = 0; j < 4; j++)
        xv[j] = __builtin_nontemporal_load(xn + c4 + 4 * j);
    }
    __syncthreads();                             // prev chunk's frag reads done
    #pragma unroll
    for (int j = 0; j < 4; j++)                  // col = c4*4 + j*16, half-chunk ok
      *((u16x4*)(hA + sw64(sr, c4 * 4 + j * 16))) = hv[j];
    __syncthreads();
    #pragma unroll
    for (int s = 0; s < 2; s++) {
      u16x8 bf = w1f[kc * 2 + s];
      #pragma unroll
      for (int mt = 0; mt < 4; mt++) {
        u16x8 af = *((const u16x8*)(hA + sw64(mt * 16 + l15, s * 32 + quad * 8)));
        acc1[mt] = mfma16(af, bf, acc1[mt]);
      }
    }
  }
  __syncthreads();                               // xs dead; hA becomes h1
  {
    float bias = b1[wave * 16 + l15];            // wave owns hid cols w*16..+15
    #pragma unroll
    for (int mt = 0; mt < 4; mt++)
      #pragma unroll
      for (int r = 0; r < 4; r++) {
        float v = acc1[mt][r] + bias;
        hA[sw64(mt * 16 + quad * 4 + r, wave * 16 + l15)] = f2bfn(v > 0.f ? v : 0.f);
      }
  }
  __syncthreads();                               // h1 complete

  // ===== GEMM2: h2 = relu(h1 @ W2^T + b2), K=64; wave owns cols w*64..+63 =====
  {
    u16x8 b2f[4][2];
    float bias2[4];
    #pragma unroll
    for (int nt = 0; nt < 4; nt++) {
      int col = wave * 64 + nt * 16 + l15;
      bias2[nt] = b2[col];
      #pragma unroll
      for (int s = 0; s < 2; s++)
        b2f[nt][s] = *((const u16x8*)(w2b + col * HID_D + s * 32 + quad * 8));
    }
    #pragma unroll
    for (int mt = 0; mt < 4; mt++) {
      u16x8 a0 = *((const u16x8*)(hA + sw64(mt * 16 + l15, 0 + quad * 8)));
      u16x8 a1 = *((const u16x8*)(hA + sw64(mt * 16 + l15, 32 + quad * 8)));
      #pragma unroll
      for (int nt = 0; nt < 4; nt++) {
        f32x4 acc = (f32x4){0.f, 0.f, 0.f, 0.f};
        acc = mfma16(a0, b2f[nt][0], acc);
        acc = mfma16(a1, b2f[nt][1], acc);
        #pragma unroll
        for (int r = 0; r < 4; r++) {
          float v = acc[r] + bias2[nt];
          hB[sw256(mt * 16 + quad * 4 + r, wave * 64 + nt * 16 + l15)] =
              f2bfn(v > 0.f ? v : 0.f);
        }
      }
    }
  }
  __syncthreads();                               // h2s complete; hA free (scratch)

  float* wnorm = (float*)hA;                     // [4][64] rownorm partials
  float* wkey = (float*)hA + 256;                // [4][64] packed max keys
  int* idxs = (int*)((float*)hA + 512);          // [64]

  // ===== G3: lat in regs -> rownorm partials (wave owns cols w*64..+63) =====
  {
    float rn[16];
    #pragma unroll
    for (int i = 0; i < 16; i++) rn[i] = 0.f;
    #pragma unroll
    for (int np = 0; np < 2; np++) {
      u16x8 b3f[2][8];
      float bias3[2];
      #pragma unroll
      for (int tt = 0; tt < 2; tt++) {
        int col = wave * 64 + (np * 2 + tt) * 16 + l15;
        bias3[tt] = bmu[col];
        #pragma unroll
        for (int s = 0; s < 8; s++)
          b3f[tt][s] = *((const u16x8*)(wmub + col * OUT_D + s * 32 + quad * 8));
      }
      #pragma unroll
      for (int mt = 0; mt < 4; mt++) {
        f32x4 aa = (f32x4){0.f, 0.f, 0.f, 0.f}, ab = (f32x4){0.f, 0.f, 0.f, 0.f};
        #pragma unroll
        for (int s = 0; s < 8; s++) {
          u16x8 af = *((const u16x8*)(hB + sw256(mt * 16 + l15, s * 32 + quad * 8)));
          aa = mfma16(af, b3f[0][s], aa);
          ab = mfma16(af, b3f[1][s], ab);
        }
        #pragma unroll
        for (int r = 0; r < 4; r++) {
          float v0 = aa[r] + bias3[0];           // NO relu on lat
          float v1 = ab[r] + bias3[1];
          rn[mt * 4 + r] += v0 * v0 + v1 * v1;
        }
      }
    }
    #pragma unroll
    for (int off = 1; off < 16; off <<= 1)
      #pragma unroll
      for (int i = 0; i < 16; i++) rn[i] += __shfl_xor(rn[i], off, 64);
    if (l15 == 0)
      #pragma unroll
      for (int mt = 0; mt < 4; mt++)
        #pragma unroll
        for (int r = 0; r < 4; r++)
          wnorm[wave * 64 + mt * 16 + quad * 4 + r] = rn[mt * 4 + r];
  }

  // ===== G4: argmax_p (h2.P2[p] + cinit[p]); wave owns protos w*256..+255 =====
  {
    float mk[16];
    #pragma unroll
    for (int i = 0; i < 16; i++) mk[i] = -3.4e38f;
    #pragma unroll
    for (int g = 0; g < 8; g++) {
      int p0 = wave * 256 + g * 32;
      u16x8 bpf[2][8];
      #pragma unroll
      for (int tt = 0; tt < 2; tt++)
        #pragma unroll
        for (int s = 0; s < 8; s++)
          bpf[tt][s] =
              *((const u16x8*)(p2b + (p0 + tt * 16 + l15) * OUT_D + s * 32 + quad * 8));
      float c0 = cinit[p0 + l15];
      float c1 = cinit[p0 + 16 + l15];
      unsigned i0 = (unsigned)(p0 + l15), i1 = (unsigned)(p0 + 16 + l15);
      #pragma unroll
      for (int mt = 0; mt < 4; mt++) {
        f32x4 aa = (f32x4){c0, c0, c0, c0};
        f32x4 ab = (f32x4){c1, c1, c1, c1};
        #pragma unroll
        for (int s = 0; s < 8; s++) {
          u16x8 af = *((const u16x8*)(hB + sw256(mt * 16 + l15, s * 32 + quad * 8)));
          aa = mfma16(af, bpf[0][s], aa);
          ab = mfma16(af, bpf[1][s], ab);
        }
        #pragma unroll
        for (int r = 0; r < 4; r++) {
          unsigned ka = (__builtin_bit_cast(unsigned, aa[r]) & 0xFFFFFC00u) | i0;
          unsigned kb = (__builtin_bit_cast(unsigned, ab[r]) & 0xFFFFFC00u) | i1;
          mk[mt * 4 + r] = fmaxf(fmaxf(mk[mt * 4 + r], __builtin_bit_cast(float, ka)),
                                 __builtin_bit_cast(float, kb));
        }
      }
    }
    #pragma unroll
    for (int off = 1; off < 16; off <<= 1)
      #pragma unroll
      for (int i = 0; i < 16; i++) mk[i] = fmaxf(mk[i], __shfl_xor(mk[i], off, 64));
    if (l15 == 0)
      #pragma unroll
      for (int mt = 0; mt < 4; mt++)
        #pragma unroll
        for (int r = 0; r < 4; r++)
          wkey[wave * 64 + mt * 16 + quad * 4 + r] = mk[mt * 4 + r];
  }
  __syncthreads();

  // ===== final per-row reduce: idx, loss_row = -2*maxkey + ||lat||^2 =====
  if (tid < 64) {
    float k = wkey[tid];
    k = fmaxf(k, wkey[64 + tid]);
    k = fmaxf(k, wkey[128 + tid]);
    k = fmaxf(k, wkey[192 + tid]);
    float nrm = wnorm[tid] + wnorm[64 + tid] + wnorm[128 + tid] + wnorm[192 + tid];
    idxs[tid] = (int)(__builtin_bit_cast(unsigned, k) & 1023u);
    float lrow = nrm - 2.f * k;
    for (int off = 32; off; off >>= 1) lrow += __shfl_xor(lrow, off, 64);
    if (tid == 0) atomicAdd(loss_accum, lrow);
  }
  __syncthreads();

  // ===== epilogue: out = protos[idx]; per instr lanes 0-3 = one full 64B line
  {
    int r = tid >> 2;
    int idx = idxs[r];
    const f32x4* qp = (const f32x4*)(protos + (size_t)idx * OUT_D);
    f32x4* op = (f32x4*)(out + (rowbase + r) * OUT_D);
    #pragma unroll
    for (int j = 0; j < 16; j++) {
      f32x4 q = qp[c4 + 4 * j];
      __builtin_nontemporal_store(q, op + c4 + 4 * j);
    }
  }
}

extern "C" void kernel_launch(void* const* d_in, const int* in_sizes, int n_in,
                              void* d_out, int out_size, void* d_ws, size_t ws_size,
                              hipStream_t stream) {
  const float* x = (const float*)d_in[0];
  const float* W1 = (const float*)d_in[1];
  const float* b1 = (const float*)d_in[2];
  const float* W2 = (const float*)d_in[3];
  const float* b2 = (const float*)d_in[4];
  const float* Wmu = (const float*)d_in[5];
  const float* bmu = (const float*)d_in[6];
  const float* protos = (const float*)d_in[7];
  char* ws = (char*)d_ws;
  u16* p2b = (u16*)ws;                           // 512 KB  (protos @ Wmu, bf16)
  u16* w1b = (u16*)(ws + 524288);                // 64 KB
  u16* w2b = (u16*)(ws + 589824);                // 32 KB
  u16* wmub = (u16*)(ws + 622592);               // 128 KB
  float* cinit = (float*)(ws + 753664);          // 4 KB
  float* loss = (float*)(ws + 757760);           // 4 B
  float* out = (float*)d_out;

  prep_w<<<dim3(448), dim3(256), 0, stream>>>(W1, W2, Wmu, w1b, w2b, wmub, loss);
  prep_p<<<dim3(256), dim3(256), 0, stream>>>(protos, Wmu, bmu, p2b, cinit);
  vq_fused<<<dim3(2048), dim3(256), 0, stream>>>(x, b1, b2, bmu, protos, w1b, w2b,
                                                 wmub, p2b, cinit, out, loss);
  fin<<<dim3(1), dim3(1), 0, stream>>>(loss, out);
}

// Round 4
// 698.194 us; speedup vs baseline: 1.1302x; 1.1009x over previous
//
#include <hip/hip_runtime.h>

// VQ-VAE fused forward on gfx950 — v4 (full-line memory requests), resubmit.
// Prior bench run died with an infra error (container failed twice, no kernel
// telemetry); kernel audited (frag-map bijections, bounds, no forbidden API)
// and resubmitted unchanged.
// v3 structure (proto-folded scoring, 40 KB LDS, 4 blocks/CU, XCD swizzle)
// unchanged. New vs v3: ALL weight arrays re-laid-out in MFMA-frag order so
// every weight load is a wave-contiguous 1 KB request (8 full 128B lines);
// x loads and out stores remapped to 8 threads/row so each instruction covers
// full 128B lines. Attacks the measured 3.1 TB/s (= half of achievable) pin:
// 64B-granule requests at the request-rate ceiling.

typedef unsigned short u16;
typedef float f32x4 __attribute__((ext_vector_type(4)));
typedef __bf16 bf16x8 __attribute__((ext_vector_type(8)));
typedef unsigned short u16x8 __attribute__((ext_vector_type(8)));
typedef unsigned short u16x4 __attribute__((ext_vector_type(4)));

#define N_ROWS 131072
#define IN_D 512
#define HID_D 64
#define OUT_D 256
#define K_P 1024

__device__ __forceinline__ u16 f2bfn(float f) {
  return __builtin_bit_cast(u16, (__bf16)f);
}
__device__ __forceinline__ f32x4 mfma16(u16x8 a, u16x8 b, f32x4 c) {
  return __builtin_amdgcn_mfma_f32_16x16x32_bf16(
      __builtin_bit_cast(bf16x8, a), __builtin_bit_cast(bf16x8, b), c, 0, 0, 0);
}
// XOR-swizzled LDS addressing (u16 units), 8-col chunks stay contiguous.
__device__ __forceinline__ int sw64(int row, int col) {   // [64][64]
  return row * 64 + ((((col >> 3) ^ (row & 7)) & 7) << 3) + (col & 7);
}
__device__ __forceinline__ int sw256(int row, int col) {  // [64][256]
  return row * 256 + ((((col >> 3) ^ (row & 15)) & 31) << 3) + (col & 7);
}

// ---------------- prep kernels ----------------
// Frag-order layouts: arr[f*512 + l15*32 + (quad*8+j)] holds element
// [row(f,l15)][col(f) + quad*8 + j] of the source weight (bf16).
__global__ void prep_w(const float* __restrict__ W1, const float* __restrict__ W2,
                       const float* __restrict__ Wmu, u16* __restrict__ w1a,
                       u16* __restrict__ w2a, u16* __restrict__ wmua,
                       float* __restrict__ loss_accum) {
  int i = blockIdx.x * 256 + threadIdx.x;   // grid 448*256 = 114688 exactly
  if (i == 0) *loss_accum = 0.f;
  if (i < 32768) {                          // W1: f = w*16+s  (64 frags)
    int a = i;
    int f = a >> 9, r = (a >> 5) & 15, c = a & 31;
    int w = f >> 4, s = f & 15;
    w1a[a] = f2bfn(W1[(w * 16 + r) * IN_D + s * 32 + c]);
  } else if (i < 49152) {                   // W2: f = w*8+nt*2+s  (32 frags)
    int a = i - 32768;
    int f = a >> 9, r = (a >> 5) & 15, c = a & 31;
    int w = f >> 3, nt = (f >> 1) & 3, s = f & 1;
    w2a[a] = f2bfn(W2[(w * 64 + nt * 16 + r) * HID_D + s * 32 + c]);
  } else {                                  // Wmu: f = w*32+g2*8+s (128 frags)
    int a = i - 49152;
    int f = a >> 9, r = (a >> 5) & 15, c = a & 31;
    int w = f >> 5, g2 = (f >> 3) & 3, s = f & 7;
    wmua[a] = f2bfn(Wmu[(w * 64 + g2 * 16 + r) * OUT_D + s * 32 + c]);
  }
}

// P2[p][k] = sum_j protos[p][j] * Wmu[j][k]  (f32 accum, bf16 store, frag order)
// cinit[p] = protos[p].bmu - 0.5*||protos[p]||^2   (f32)
__global__ void prep_p(const float* __restrict__ protos, const float* __restrict__ Wmu,
                       const float* __restrict__ bmu, u16* __restrict__ p2a,
                       float* __restrict__ cinit) {
  __shared__ float prow[4][256];
  const int b = blockIdx.x, t = threadIdx.x;   // 256 blocks x 4 protos
  const int wv = t >> 6, lane = t & 63;
  #pragma unroll
  for (int i = 0; i < 4; i++) prow[i][t] = protos[(b * 4 + i) * 256 + t];
  __syncthreads();
  float acc[4] = {0.f, 0.f, 0.f, 0.f};
  #pragma unroll 4
  for (int j = 0; j < 256; j++) {
    float w = Wmu[j * 256 + t];
    acc[0] += prow[0][j] * w; acc[1] += prow[1][j] * w;
    acc[2] += prow[2][j] * w; acc[3] += prow[3][j] * w;
  }
  // frag-order write: p -> (w=p>>8, g=(p>>5)&7, tt=(p>>4)&1, l15=p&15), k=t
  #pragma unroll
  for (int i = 0; i < 4; i++) {
    int p = b * 4 + i;
    int f = (p >> 8) * 128 + ((p >> 5) & 7) * 16 + ((p >> 4) & 1) * 8 + (t >> 5);
    p2a[f * 512 + (p & 15) * 32 + (t & 31)] = f2bfn(acc[i]);
  }
  // wave wv reduces proto b*4+wv
  float part = 0.f;
  #pragma unroll
  for (int c = 0; c < 4; c++) {
    float v = prow[wv][lane + c * 64];
    part += v * bmu[lane + c * 64] - 0.5f * v * v;
  }
  for (int off = 32; off; off >>= 1) part += __shfl_xor(part, off, 64);
  if (lane == 0) cinit[b * 4 + wv] = part;
}

__global__ void fin(const float* __restrict__ loss_accum, float* __restrict__ out) {
  out[(size_t)N_ROWS * OUT_D] = loss_accum[0] * (1.25f / ((float)N_ROWS * (float)OUT_D));
  out[(size_t)N_ROWS * OUT_D + 1] = 0.f;  // capacity
}

// ---------------- fused main kernel ----------------
__global__ __launch_bounds__(256, 4) void vq_fused(
    const float* __restrict__ x, const float* __restrict__ b1,
    const float* __restrict__ b2, const float* __restrict__ bmu,
    const float* __restrict__ protos, const u16* __restrict__ w1a,
    const u16* __restrict__ w2a, const u16* __restrict__ wmua,
    const u16* __restrict__ p2a, const float* __restrict__ cinit,
    float* __restrict__ out, float* __restrict__ loss_accum) {
  __shared__ uint4 smem4[2560];                  // 40 KB exactly -> 4 blocks/CU
  u16* hA = (u16*)smem4;                         // 8 KB: xs chunk -> h1 -> scratch
  u16* hB = (u16*)smem4 + 4096;                  // 32 KB: h2s [64][256]

  const int tid = threadIdx.x;
  const int wave = tid >> 6;
  const int lane = tid & 63;
  const int quad = lane >> 4;
  const int l15 = lane & 15;
  const int fragoff = l15 * 32 + quad * 8;       // lane offset within a 512-u16 frag
  // bijective XCD swizzle: 2048 blocks = 8 XCDs x 256 contiguous tiles
  const int bid = blockIdx.x;
  const int swz = (bid & 7) * 256 + (bid >> 3);
  const long rowbase = (long)swz * 64;

  // ===== GEMM1: h1 = relu(x @ W1^T + b1); K=512 in 8 chunks of 64 =====
  u16x8 w1f[16];                                 // all W1 B-frags hoisted
  #pragma unroll
  for (int s = 0; s < 16; s++)
    w1f[s] = *((const u16x8*)(w1a + (wave * 16 + s) * 512 + fragoff));

  f32x4 acc1[4];
  #pragma unroll
  for (int mt = 0; mt < 4; mt++) acc1[mt] = (f32x4){0.f, 0.f, 0.f, 0.f};

  // stage map: 8 threads/row, two row-halves; per instr 8 rows x 128B full lines
  const int r8 = tid >> 3, c8 = tid & 7;
  const float* xr0 = x + (rowbase + r8) * IN_D;
  const float* xr1 = x + (rowbase + r8 + 32) * IN_D;
  f32x4 xv[4];                                   // [rowhalf*2 + jj]
  xv[0] = __builtin_nontemporal_load((const f32x4*)xr0 + c8);
  xv[1] = __builtin_nontemporal_load((const f32x4*)xr0 + c8 + 8);
  xv[2] = __builtin_nontemporal_load((const f32x4*)xr1 + c8);
  xv[3] = __builtin_nontemporal_load((const f32x4*)xr1 + c8 + 8);

  #pragma unroll
  for (int kc = 0; kc < 8; kc++) {
    u16x4 hv[4];
    #pragma unroll
    for (int q = 0; q < 4; q++) {
      hv[q][0] = f2bfn(xv[q][0]); hv[q][1] = f2bfn(xv[q][1]);
      hv[q][2] = f2bfn(xv[q][2]); hv[q][3] = f2bfn(xv[q][3]);
    }
    if (kc < 7) {                                // prefetch next chunk (T14)
      const int base = (kc + 1) * 16;
      xv[0] = __builtin_nontemporal_load((const f32x4*)xr0 + base + c8);
      xv[1] = __builtin_nontemporal_load((const f32x4*)xr0 + base + c8 + 8);
      xv[2] = __builtin_nontemporal_load((const f32x4*)xr1 + base + c8);
      xv[3] = __builtin_nontemporal_load((const f32x4*)xr1 + base + c8 + 8);
    }
    __syncthreads();                             // prev chunk's frag reads done
    *((u16x4*)(hA + sw64(r8, c8 * 4))) = hv[0];
    *((u16x4*)(hA + sw64(r8, c8 * 4 + 32))) = hv[1];
    *((u16x4*)(hA + sw64(r8 + 32, c8 * 4))) = hv[2];
    *((u16x4*)(hA + sw64(r8 + 32, c8 * 4 + 32))) = hv[3];
    __syncthreads();
    #pragma unroll
    for (int s = 0; s < 2; s++) {
      u16x8 bf = w1f[kc * 2 + s];
      #pragma unroll
      for (int mt = 0; mt < 4; mt++) {
        u16x8 af = *((const u16x8*)(hA + sw64(mt * 16 + l15, s * 32 + quad * 8)));
        acc1[mt] = mfma16(af, bf, acc1[mt]);
      }
    }
  }
  __syncthreads();                               // xs dead; hA becomes h1
  {
    float bias = b1[wave * 16 + l15];            // wave owns hid cols w*16..+15
    #pragma unroll
    for (int mt = 0; mt < 4; mt++)
      #pragma unroll
      for (int r = 0; r < 4; r++) {
        float v = acc1[mt][r] + bias;
        hA[sw64(mt * 16 + quad * 4 + r, wave * 16 + l15)] = f2bfn(v > 0.f ? v : 0.f);
      }
  }
  __syncthreads();                               // h1 complete

  // ===== GEMM2: h2 = relu(h1 @ W2^T + b2), K=64; wave owns cols w*64..+63 =====
  {
    u16x8 b2f[4][2];
    float bias2[4];
    #pragma unroll
    for (int nt = 0; nt < 4; nt++) {
      bias2[nt] = b2[wave * 64 + nt * 16 + l15];
      #pragma unroll
      for (int s = 0; s < 2; s++)
        b2f[nt][s] = *((const u16x8*)(w2a + (wave * 8 + nt * 2 + s) * 512 + fragoff));
    }
    #pragma unroll
    for (int mt = 0; mt < 4; mt++) {
      u16x8 a0 = *((const u16x8*)(hA + sw64(mt * 16 + l15, 0 + quad * 8)));
      u16x8 a1 = *((const u16x8*)(hA + sw64(mt * 16 + l15, 32 + quad * 8)));
      #pragma unroll
      for (int nt = 0; nt < 4; nt++) {
        f32x4 acc = (f32x4){0.f, 0.f, 0.f, 0.f};
        acc = mfma16(a0, b2f[nt][0], acc);
        acc = mfma16(a1, b2f[nt][1], acc);
        #pragma unroll
        for (int r = 0; r < 4; r++) {
          float v = acc[r] + bias2[nt];
          hB[sw256(mt * 16 + quad * 4 + r, wave * 64 + nt * 16 + l15)] =
              f2bfn(v > 0.f ? v : 0.f);
        }
      }
    }
  }
  __syncthreads();                               // h2s complete; hA free (scratch)

  float* wnorm = (float*)hA;                     // [4][64] rownorm partials
  float* wkey = (float*)hA + 256;                // [4][64] packed max keys
  int* idxs = (int*)((float*)hA + 512);          // [64]

  // ===== G3: lat in regs -> rownorm partials (wave owns cols w*64..+63) =====
  {
    float rn[16];
    #pragma unroll
    for (int i = 0; i < 16; i++) rn[i] = 0.f;
    #pragma unroll
    for (int np = 0; np < 2; np++) {
      u16x8 b3f[2][8];
      float bias3[2];
      #pragma unroll
      for (int tt = 0; tt < 2; tt++) {
        bias3[tt] = bmu[wave * 64 + (np * 2 + tt) * 16 + l15];
        #pragma unroll
        for (int s = 0; s < 8; s++)
          b3f[tt][s] = *((const u16x8*)(wmua +
              ((wave * 4 + np * 2 + tt) * 8 + s) * 512 + fragoff));
      }
      #pragma unroll
      for (int mt = 0; mt < 4; mt++) {
        f32x4 aa = (f32x4){0.f, 0.f, 0.f, 0.f}, ab = (f32x4){0.f, 0.f, 0.f, 0.f};
        #pragma unroll
        for (int s = 0; s < 8; s++) {
          u16x8 af = *((const u16x8*)(hB + sw256(mt * 16 + l15, s * 32 + quad * 8)));
          aa = mfma16(af, b3f[0][s], aa);
          ab = mfma16(af, b3f[1][s], ab);
        }
        #pragma unroll
        for (int r = 0; r < 4; r++) {
          float v0 = aa[r] + bias3[0];           // NO relu on lat
          float v1 = ab[r] + bias3[1];
          rn[mt * 4 + r] += v0 * v0 + v1 * v1;
        }
      }
    }
    #pragma unroll
    for (int off = 1; off < 16; off <<= 1)
      #pragma unroll
      for (int i = 0; i < 16; i++) rn[i] += __shfl_xor(rn[i], off, 64);
    if (l15 == 0)
      #pragma unroll
      for (int mt = 0; mt < 4; mt++)
        #pragma unroll
        for (int r = 0; r < 4; r++)
          wnorm[wave * 64 + mt * 16 + quad * 4 + r] = rn[mt * 4 + r];
  }

  // ===== G4: argmax_p (h2.P2[p] + cinit[p]); wave owns protos w*256..+255 =====
  {
    float mk[16];
    #pragma unroll
    for (int i = 0; i < 16; i++) mk[i] = -3.4e38f;
    #pragma unroll
    for (int g = 0; g < 8; g++) {
      int p0 = wave * 256 + g * 32;
      u16x8 bpf[2][8];
      #pragma unroll
      for (int tt = 0; tt < 2; tt++)
        #pragma unroll
        for (int s = 0; s < 8; s++)
          bpf[tt][s] = *((const u16x8*)(p2a +
              (wave * 128 + g * 16 + tt * 8 + s) * 512 + fragoff));
      float c0 = cinit[p0 + l15];
      float c1 = cinit[p0 + 16 + l15];
      unsigned i0 = (unsigned)(p0 + l15), i1 = (unsigned)(p0 + 16 + l15);
      #pragma unroll
      for (int mt = 0; mt < 4; mt++) {
        f32x4 aa = (f32x4){c0, c0, c0, c0};
        f32x4 ab = (f32x4){c1, c1, c1, c1};
        #pragma unroll
        for (int s = 0; s < 8; s++) {
          u16x8 af = *((const u16x8*)(hB + sw256(mt * 16 + l15, s * 32 + quad * 8)));
          aa = mfma16(af, bpf[0][s], aa);
          ab = mfma16(af, bpf[1][s], ab);
        }
        #pragma unroll
        for (int r = 0; r < 4; r++) {
          unsigned ka = (__builtin_bit_cast(unsigned, aa[r]) & 0xFFFFFC00u) | i0;
          unsigned kb = (__builtin_bit_cast(unsigned, ab[r]) & 0xFFFFFC00u) | i1;
          mk[mt * 4 + r] = fmaxf(fmaxf(mk[mt * 4 + r], __builtin_bit_cast(float, ka)),
                                 __builtin_bit_cast(float, kb));
        }
      }
    }
    #pragma unroll
    for (int off = 1; off < 16; off <<= 1)
      #pragma unroll
      for (int i = 0; i < 16; i++) mk[i] = fmaxf(mk[i], __shfl_xor(mk[i], off, 64));
    if (l15 == 0)
      #pragma unroll
      for (int mt = 0; mt < 4; mt++)
        #pragma unroll
        for (int r = 0; r < 4; r++)
          wkey[wave * 64 + mt * 16 + quad * 4 + r] = mk[mt * 4 + r];
  }
  __syncthreads();

  // ===== final per-row reduce: idx, loss_row = -2*maxkey + ||lat||^2 =====
  if (tid < 64) {
    float k = wkey[tid];
    k = fmaxf(k, wkey[64 + tid]);
    k = fmaxf(k, wkey[128 + tid]);
    k = fmaxf(k, wkey[192 + tid]);
    float nrm = wnorm[tid] + wnorm[64 + tid] + wnorm[128 + tid] + wnorm[192 + tid];
    idxs[tid] = (int)(__builtin_bit_cast(unsigned, k) & 1023u);
    float lrow = nrm - 2.f * k;
    for (int off = 32; off; off >>= 1) lrow += __shfl_xor(lrow, off, 64);
    if (tid == 0) atomicAdd(loss_accum, lrow);
  }
  __syncthreads();

  // ===== epilogue: out = protos[idx]; 8 threads/row -> full 128B lines =====
  {
    #pragma unroll
    for (int half = 0; half < 2; half++) {
      int r = r8 + half * 32;
      int idx = idxs[r];
      const f32x4* qp = (const f32x4*)(protos + (size_t)idx * OUT_D);
      f32x4* op = (f32x4*)(out + (rowbase + r) * OUT_D);
      #pragma unroll
      for (int j = 0; j < 8; j++) {
        f32x4 q = qp[c8 + 8 * j];
        __builtin_nontemporal_store(q, op + c8 + 8 * j);
      }
    }
  }
}

extern "C" void kernel_launch(void* const* d_in, const int* in_sizes, int n_in,
                              void* d_out, int out_size, void* d_ws, size_t ws_size,
                              hipStream_t stream) {
  const float* x = (const float*)d_in[0];
  const float* W1 = (const float*)d_in[1];
  const float* b1 = (const float*)d_in[2];
  const float* W2 = (const float*)d_in[3];
  const float* b2 = (const float*)d_in[4];
  const float* Wmu = (const float*)d_in[5];
  const float* bmu = (const float*)d_in[6];
  const float* protos = (const float*)d_in[7];
  char* ws = (char*)d_ws;
  u16* p2a = (u16*)ws;                           // 512 KB  (frag-order P2)
  u16* w1a = (u16*)(ws + 524288);                // 64 KB   (frag-order W1)
  u16* w2a = (u16*)(ws + 589824);                // 32 KB   (frag-order W2)
  u16* wmua = (u16*)(ws + 622592);               // 128 KB  (frag-order Wmu)
  float* cinit = (float*)(ws + 753664);          // 4 KB
  float* loss = (float*)(ws + 757760);           // 4 B
  float* out = (float*)d_out;

  prep_w<<<dim3(448), dim3(256), 0, stream>>>(W1, W2, Wmu, w1a, w2a, wmua, loss);
  prep_p<<<dim3(256), dim3(256), 0, stream>>>(protos, Wmu, bmu, p2a, cinit);
  vq_fused<<<dim3(2048), dim3(256), 0, stream>>>(x, b1, b2, bmu, protos, w1a, w2a,
                                                 wmua, p2a, cinit, out, loss);
  fin<<<dim3(1), dim3(1), 0, stream>>>(loss, out);
}